// Round 12
// baseline (393.571 us; speedup 1.0000x reference)
//
#include <hip/hip_runtime.h>
#include <math.h>

// Problem constants (fixed by setup_inputs)
#define BB   8
#define NN   4096
#define DD   128
#define HH   4
#define CC   32
#define LLAY 3
#define DEG  16
#define NSEG (BB*NN)      // 32768
#define FF   512

typedef __bf16 bf16;
typedef __bf16 bf16x4 __attribute__((ext_vector_type(4)));
typedef __bf16 bf16x8 __attribute__((ext_vector_type(8)));
typedef float  f32x4  __attribute__((ext_vector_type(4)));

// ---------------------------------------------------------------------------
// bf16 MFMA GEMM (m97 structure): C[M,N] = A[M,K] @ Bt[N,K]^T + bias
// 128x128 tile, BK=32, 4 waves (2x2), 4x4 frags of 16x16x32 per wave.
// global_load_lds width=16, linear LDS, 4-way XOR k-chunk swizzle.
// ACT=1 -> SiLU. Used for: fused lin_l|lin_r (N=256), FF1 (N=512).
// ---------------------------------------------------------------------------
template<int ACT, typename OutT>
__global__ __launch_bounds__(256) void mfma_gemm(
    const bf16* __restrict__ A, const bf16* __restrict__ Bt,
    const float* __restrict__ bias, OutT* __restrict__ C,
    int M, int N, int K)
{
    __shared__ bf16 As[128 * 32];
    __shared__ bf16 Bs[128 * 32];

    const int tid  = threadIdx.x;
    const int wave = tid >> 6;
    const int lane = tid & 63;
    const int wr   = wave >> 1;
    const int wc   = wave & 1;
    const int bm   = blockIdx.x * 128;
    const int bn   = blockIdx.y * 128;

    const int lr   = lane & 15;
    const int lkp  = ((lane >> 4) ^ (lane & 3)) * 8;
    const int srow = lane >> 2;
    const int skb  = ((lane & 3) ^ ((lane >> 2) & 3)) * 8;

    f32x4 acc[4][4] = {};

    for (int k0 = 0; k0 < K; k0 += 32) {
        #pragma unroll
        for (int r = 0; r < 2; ++r) {
            int chunk = wave * 2 + r;
            const bf16* ga = A + (size_t)(bm + chunk * 16 + srow) * K + k0 + skb;
            __builtin_amdgcn_global_load_lds(
                (const __attribute__((address_space(1))) void*)ga,
                (__attribute__((address_space(3))) void*)(As + chunk * 512),
                16, 0, 0);
            const bf16* gb = Bt + (size_t)(bn + chunk * 16 + srow) * K + k0 + skb;
            __builtin_amdgcn_global_load_lds(
                (const __attribute__((address_space(1))) void*)gb,
                (__attribute__((address_space(3))) void*)(Bs + chunk * 512),
                16, 0, 0);
        }
        __syncthreads();

        bf16x8 af[4], bfr[4];
        #pragma unroll
        for (int i = 0; i < 4; ++i)
            af[i] = *(const bf16x8*)&As[(wr * 64 + i * 16 + lr) * 32 + lkp];
        #pragma unroll
        for (int j = 0; j < 4; ++j)
            bfr[j] = *(const bf16x8*)&Bs[(wc * 64 + j * 16 + lr) * 32 + lkp];
        #pragma unroll
        for (int i = 0; i < 4; ++i)
            #pragma unroll
            for (int j = 0; j < 4; ++j)
                acc[i][j] = __builtin_amdgcn_mfma_f32_16x16x32_bf16(
                    af[i], bfr[j], acc[i][j], 0, 0, 0);
        __syncthreads();
    }

    const int orow = (lane >> 4) * 4;
    #pragma unroll
    for (int j = 0; j < 4; ++j) {
        int gcol = bn + wc * 64 + j * 16 + lr;
        float bv = bias[gcol];
        #pragma unroll
        for (int i = 0; i < 4; ++i) {
            int grow0 = bm + wr * 64 + i * 16 + orow;
            #pragma unroll
            for (int q = 0; q < 4; ++q) {
                float t = acc[i][j][q] + bv;
                if (ACT == 1) t = t / (1.0f + __expf(-t));   // SiLU
                C[(size_t)(grow0 + q) * N + gcol] = (OutT)t;
            }
        }
    }
}

// ---------------------------------------------------------------------------
// Fused FF2 GEMM + residual + LayerNorm2. N=128 (one tile covers full rows),
// K=512, M=NSEG. Same MFMA core; epilogue stages the f32 tile in LDS (64 KB,
// aliasing the staging buffers after the last barrier), then per-row LN:
// row's 128 channels live in one wave (lane = 2 ch), identical math to the
// old ln_res_kernel — bit-exact vs the unfused path (fp32 store/load exact).
// OutT: bf16 (next-layer lin input XB) or float (final output).
// ---------------------------------------------------------------------------
template<typename OutT>
__global__ __launch_bounds__(256) void ff2_ln_kernel(
    const bf16* __restrict__ A,      // HID [M][512]
    const bf16* __restrict__ Bt,     // WT2 slice [128][512]
    const float* __restrict__ bias,  // ff2_b
    const float* __restrict__ resid, // XG [M][128]
    const float* __restrict__ g, const float* __restrict__ b,  // ln2
    OutT* __restrict__ out)
{
    __shared__ float pool[128 * 128];            // 64 KB
    bf16* As = (bf16*)pool;                      // [128*32] (8 KB)
    bf16* Bs = (bf16*)(pool + 2048);             // [128*32] (8 KB)

    const int tid  = threadIdx.x;
    const int wave = tid >> 6;
    const int lane = tid & 63;
    const int wr   = wave >> 1;
    const int wc   = wave & 1;
    const int bm   = blockIdx.x * 128;

    const int lr   = lane & 15;
    const int lkp  = ((lane >> 4) ^ (lane & 3)) * 8;
    const int srow = lane >> 2;
    const int skb  = ((lane & 3) ^ ((lane >> 2) & 3)) * 8;

    f32x4 acc[4][4] = {};

    for (int k0 = 0; k0 < 512; k0 += 32) {
        #pragma unroll
        for (int r = 0; r < 2; ++r) {
            int chunk = wave * 2 + r;
            const bf16* ga = A + (size_t)(bm + chunk * 16 + srow) * 512 + k0 + skb;
            __builtin_amdgcn_global_load_lds(
                (const __attribute__((address_space(1))) void*)ga,
                (__attribute__((address_space(3))) void*)(As + chunk * 512),
                16, 0, 0);
            const bf16* gb = Bt + (size_t)(chunk * 16 + srow) * 512 + k0 + skb;
            __builtin_amdgcn_global_load_lds(
                (const __attribute__((address_space(1))) void*)gb,
                (__attribute__((address_space(3))) void*)(Bs + chunk * 512),
                16, 0, 0);
        }
        __syncthreads();

        bf16x8 af[4], bfr[4];
        #pragma unroll
        for (int i = 0; i < 4; ++i)
            af[i] = *(const bf16x8*)&As[(wr * 64 + i * 16 + lr) * 32 + lkp];
        #pragma unroll
        for (int j = 0; j < 4; ++j)
            bfr[j] = *(const bf16x8*)&Bs[(wc * 64 + j * 16 + lr) * 32 + lkp];
        #pragma unroll
        for (int i = 0; i < 4; ++i)
            #pragma unroll
            for (int j = 0; j < 4; ++j)
                acc[i][j] = __builtin_amdgcn_mfma_f32_16x16x32_bf16(
                    af[i], bfr[j], acc[i][j], 0, 0, 0);
        __syncthreads();    // also protects As/Bs before pool reuse below
    }

    // Epilogue 1: bias-add, stash f32 tile in LDS (rows 0..127 x cols 0..127)
    const int orow = (lane >> 4) * 4;
    #pragma unroll
    for (int j = 0; j < 4; ++j) {
        int col = wc * 64 + j * 16 + lr;
        float bv = bias[col];
        #pragma unroll
        for (int i = 0; i < 4; ++i) {
            int row0 = wr * 64 + i * 16 + orow;
            #pragma unroll
            for (int q = 0; q < 4; ++q)
                pool[(row0 + q) * 128 + col] = acc[i][j][q] + bv;
        }
    }
    __syncthreads();

    // Epilogue 2: per-row residual + LN (identical to old ln_res_kernel math)
    const int c0 = lane * 2;
    for (int it = 0; it < 32; ++it) {
        int row = wave * 32 + it;
        float2 v = { pool[row * 128 + c0], pool[row * 128 + c0 + 1] };
        float2 r = *(const float2*)(resid + (size_t)(bm + row) * DD + c0);
        v.x += r.x; v.y += r.y;

        float s = v.x + v.y;
        #pragma unroll
        for (int mk = 1; mk < 64; mk <<= 1) s += __shfl_xor(s, mk);
        const float mu = s * (1.0f / 128.0f);
        float dx = v.x - mu, dy = v.y - mu;
        float q = dx * dx + dy * dy;
        #pragma unroll
        for (int mk = 1; mk < 64; mk <<= 1) q += __shfl_xor(q, mk);
        const float rs = rsqrtf(q * (1.0f / 128.0f) + 1e-5f);

        out[(size_t)(bm + row) * DD + c0]     = (OutT)(dx * rs * g[c0]     + b[c0]);
        out[(size_t)(bm + row) * DD + c0 + 1] = (OutT)(dy * rs * g[c0 + 1] + b[c0 + 1]);
    }
}

// ---------------------------------------------------------------------------
// One-shot setup: x->bf16 plus all weight transposes/conversions.
//   idx 0..1048575            : XB (4 elems/thread)
//   then WLR / WT1 / WT2 / BLR (same logic as before, shifted)
// ---------------------------------------------------------------------------
#define CVT_XN  1048576
__global__ __launch_bounds__(256) void cvt_all(
    const float* __restrict__ x,
    const float* __restrict__ ll_w, const float* __restrict__ ll_b,
    const float* __restrict__ lr_w, const float* __restrict__ lr_b,
    const float* __restrict__ ff1_w, const float* __restrict__ ff2_w,
    bf16* __restrict__ xb, bf16* __restrict__ wlr,
    bf16* __restrict__ wt1, bf16* __restrict__ wt2, float* __restrict__ blr)
{
    int gid = blockIdx.x * 256 + threadIdx.x;
    if (gid < CVT_XN) {
        int i = gid * 4;
        float4 v = *(const float4*)(x + i);
        bf16x4 o = { (bf16)v.x, (bf16)v.y, (bf16)v.z, (bf16)v.w };
        *(bf16x4*)(xb + i) = o;
        return;
    }
    int idx = gid - CVT_XN;
    if (idx < 98304) {                             // WLR: 3*256*128
        int l = idx / 32768, e = idx % 32768;
        int n = e >> 7, k = e & 127;
        float v = (n < 128) ? ll_w[l * 16384 + k * 128 + n]
                            : lr_w[l * 16384 + k * 128 + (n - 128)];
        wlr[idx] = (bf16)v;
    } else if (idx < 294912) {                     // WT1: 3*128*512
        int r = idx - 98304;
        int l = r >> 16, e = r & 65535;
        int k = e >> 9, n = e & 511;
        wt1[l * 65536 + n * 128 + k] = (bf16)ff1_w[l * 65536 + k * 512 + n];
    } else if (idx < 491520) {                     // WT2: 3*512*128
        int r = idx - 294912;
        int l = r >> 16, e = r & 65535;
        int k = e >> 7, n = e & 127;
        wt2[l * 65536 + n * 512 + k] = (bf16)ff2_w[l * 65536 + k * 128 + n];
    } else if (idx < 492288) {                     // BLR: 3*256
        int r = idx - 491520;
        int l = r / 256, n = r % 256;
        blr[r] = (n < 128) ? ll_b[l * 128 + n] : lr_b[l * 128 + (n - 128)];
    }
}

// ---------------------------------------------------------------------------
// Fused GATv2 edge softmax + aggregate + LayerNorm1. One wave per node.
// glr: [NSEG][256] fp32, cols 0-127 = gl, 128-255 = gr.
// XCD-aware swizzle (T1): keeps each batch block's 2 MB gather set on one
// XCD's L2 (verified r10: FETCH 65.9 -> 17.6 MB). Kernel is latency/VALU
// bound; this round: pre-loaded src indices + 1-op leaky-relu (bit-exact).
// ---------------------------------------------------------------------------
__global__ __launch_bounds__(256) void gat_ln_kernel(
    const float* __restrict__ glr,
    const int* __restrict__ src, const float* __restrict__ att,
    const float* __restrict__ bias,
    const float* __restrict__ ln_g, const float* __restrict__ ln_b,
    float* __restrict__ xg, bf16* __restrict__ ln_out)
{
    const int wave = threadIdx.x >> 6;
    const int lane = threadIdx.x & 63;
    const int bid  = blockIdx.x;
    const int sb   = ((bid & 7) << 10) | (bid >> 3);   // XCD-chunked remap
    const int node = sb * 4 + wave;
    const int c0   = lane * 2;
    const int h    = lane >> 4;

    const float2 gri = *(const float2*)(glr + (size_t)node * 256 + 128 + c0);
    const float a0 = att[h * CC + (c0 & 31)];
    const float a1 = att[h * CC + ((c0 + 1) & 31)];

    int sidx[DEG];
    const int* sp = src + node * DEG;
    #pragma unroll
    for (int e = 0; e < DEG; ++e) sidx[e] = sp[e];

    float glx[DEG], gly[DEG], logit[DEG];

    #pragma unroll
    for (int e = 0; e < DEG; ++e) {
        float2 gv = *(const float2*)(glr + (size_t)sidx[e] * 256 + c0);
        glx[e] = gv.x; gly[e] = gv.y;
        float s0 = gv.x + gri.x, s1 = gv.y + gri.y;
        float v0 = fmaxf(s0, 0.2f * s0);           // leaky_relu, bit-exact
        float v1 = fmaxf(s1, 0.2f * s1);
        float p = v0 * a0 + v1 * a1;
        p += __shfl_xor(p, 1);
        p += __shfl_xor(p, 2);
        p += __shfl_xor(p, 4);
        p += __shfl_xor(p, 8);
        logit[e] = p;
    }

    float m = logit[0];
    #pragma unroll
    for (int e = 1; e < DEG; ++e) m = fmaxf(m, logit[e]);

    float den = 0.0f, accx = 0.0f, accy = 0.0f;
    #pragma unroll
    for (int e = 0; e < DEG; ++e) {
        float a = __expf(logit[e] - m);
        den += a;
        accx = fmaf(a, glx[e], accx);
        accy = fmaf(a, gly[e], accy);
    }
    float inv = 1.0f / den;
    float2 o;
    o.x = accx * inv + bias[c0];
    o.y = accy * inv + bias[c0 + 1];
    *(float2*)(xg + (size_t)node * DD + c0) = o;

    // ---- fused LayerNorm over the 128 channels held by this wave ----
    float s = o.x + o.y;
    #pragma unroll
    for (int mk = 1; mk < 64; mk <<= 1) s += __shfl_xor(s, mk);
    const float mu = s * (1.0f / 128.0f);
    float dx = o.x - mu, dy = o.y - mu;
    float q = dx * dx + dy * dy;
    #pragma unroll
    for (int mk = 1; mk < 64; mk <<= 1) q += __shfl_xor(q, mk);
    const float rs = rsqrtf(q * (1.0f / 128.0f) + 1e-5f);

    ln_out[(size_t)node * DD + c0]     = (bf16)(dx * rs * ln_g[c0]     + ln_b[c0]);
    ln_out[(size_t)node * DD + c0 + 1] = (bf16)(dy * rs * ln_g[c0 + 1] + ln_b[c0 + 1]);
}

// ---------------------------------------------------------------------------
extern "C" void kernel_launch(void* const* d_in, const int* in_sizes, int n_in,
                              void* d_out, int out_size, void* d_ws, size_t ws_size,
                              hipStream_t stream)
{
    const float* x        = (const float*)d_in[0];
    const float* lin_l_w  = (const float*)d_in[1];
    const float* lin_l_b  = (const float*)d_in[2];
    const float* lin_r_w  = (const float*)d_in[3];
    const float* lin_r_b  = (const float*)d_in[4];
    const float* att      = (const float*)d_in[5];
    const float* gat_bias = (const float*)d_in[6];
    const float* ln1_g    = (const float*)d_in[7];
    const float* ln1_b    = (const float*)d_in[8];
    const float* ff1_w    = (const float*)d_in[9];
    const float* ff1_b    = (const float*)d_in[10];
    const float* ff2_w    = (const float*)d_in[11];
    const float* ff2_b    = (const float*)d_in[12];
    const float* ln2_g    = (const float*)d_in[13];
    const float* ln2_b    = (const float*)d_in[14];
    const int*   src      = (const int*)d_in[15];     // edge_index row 0

    float* out = (float*)d_out;
    float* ws  = (float*)d_ws;

    // Workspace layout (~101 MB):
    //   fp32: GLR [NSEG][256], XG [NSEG][128]
    //   bf16: XB [NSEG][128], LN1B [NSEG][128], HID [NSEG][512],
    //         WLR 3*256*128, WT1 3*512*128, WT2 3*128*512
    //   fp32: BLR 3*256
    const size_t NV = (size_t)NSEG * DD;              // 4,194,304
    float* GLR  = ws;                                 // fused lin out (stride 256)
    float* XG   = GLR + 2 * NV;                       // GAT out (residual)
    bf16*  XB   = (bf16*)(XG + NV);                   // lin input (bf16)
    bf16*  LN1B = XB + NV;                            // LN1 out (bf16)
    bf16*  HID  = LN1B + NV;                          // FF hidden (bf16)
    bf16*  WLR  = HID + (size_t)NSEG * FF;            // lin weights^T cat
    bf16*  WT1  = WLR + (size_t)LLAY * 256 * DD;
    bf16*  WT2  = WT1 + (size_t)LLAY * FF * DD;
    float* BLR  = (float*)(WT2 + (size_t)LLAY * DD * FF);

    cvt_all<<<6018, 256, 0, stream>>>(x, lin_l_w, lin_l_b, lin_r_w, lin_r_b,
                                      ff1_w, ff2_w, XB, WLR, WT1, WT2, BLR);

    for (int l = 0; l < LLAY; ++l) {
        dim3 gLin(NSEG / 128, 256 / 128);             // (256, 2)
        mfma_gemm<0, float><<<gLin, 256, 0, stream>>>(XB, WLR + (size_t)l*256*DD,
                                                      BLR + l*256, GLR, NSEG, 256, DD);
        gat_ln_kernel<<<NSEG / 4, 256, 0, stream>>>(GLR, src, att + l*HH*CC,
                                                    gat_bias + l*DD,
                                                    ln1_g + l*DD, ln1_b + l*DD,
                                                    XG, LN1B);
        dim3 gF1(NSEG / 128, FF / 128);               // (256, 4)
        mfma_gemm<1, bf16><<<gF1, 256, 0, stream>>>(LN1B, WT1 + (size_t)l*FF*DD,
                                                    ff1_b + l*FF, HID, NSEG, FF, DD);
        if (l == LLAY - 1) {
            ff2_ln_kernel<float><<<NSEG / 128, 256, 0, stream>>>(
                HID, WT2 + (size_t)l*DD*FF, ff2_b + l*DD, XG,
                ln2_g + l*DD, ln2_b + l*DD, out);
        } else {
            ff2_ln_kernel<bf16><<<NSEG / 128, 256, 0, stream>>>(
                HID, WT2 + (size_t)l*DD*FF, ff2_b + l*DD, XG,
                ln2_g + l*DD, ln2_b + l*DD, XB);
        }
    }
}